// Round 2
// baseline (883.679 us; speedup 1.0000x reference)
//
#include <hip/hip_runtime.h>
#include <stdint.h>

// CMAALayer fused kernel, MI355X gfx950. Round 2: runtime dtype dispatch.
// Reference is fp32; harness may store tensors fp32 OR bf16. We detect on
// device (bf16 data decoded as bf16 halves never has exponent>=150; fp32
// words' low halves are random mantissa bits -> huge exponents w.h.p.) and
// run the matching template instantiation; the other exits immediately.
//
// One 256-thread block handles RT=32 rows (8 b-groups of 4 tokens):
//   stage0: X tile -> LDS (bf16, converted if fp32 input)
//   phase p in {0,1}: QKVR GEMM via mfma_f32_16x16x32_bf16 -> sQK LDS;
//     3-neighbor softmax attention + sigmoid(R)*V -> sAO LDS + attn out.
//   stage3: AO @ Wo^T (MFMA) + residual -> sY(fp32) -> two-pass LN -> y.

#define D_DIM   256
#define H_NUM   8
#define DH      32
#define RT      32
#define ROWS_TOT 131072
#define Y_SZ    33554432          // 131072*256
#define SCALE_F 0.17677669529663687f

#define SX_LD   264   // shorts
#define SQK_LD  520   // shorts
#define SAO_LD  264   // shorts
#define SY_LD   260   // floats (aliases sQK storage)

typedef __attribute__((ext_vector_type(8))) short bf16x8;
typedef __attribute__((ext_vector_type(4))) float f32x4;

__device__ __forceinline__ float b2f(uint16_t s) {
    union { uint32_t u; float f; } c; c.u = ((uint32_t)s) << 16; return c.f;
}
__device__ __forceinline__ uint16_t f2b(float f) {
    union { float f; uint32_t u; } c; c.f = f;
    return (uint16_t)((c.u + 0x7fffu + ((c.u >> 16) & 1u)) >> 16);
}
// 8 consecutive fp32 -> bf16x8 (RNE)
__device__ __forceinline__ bf16x8 cvt8(const float* p) {
    const float4 a = *(const float4*)p;
    const float4 b = *(const float4*)(p + 4);
    bf16x8 r;
    r[0] = (short)f2b(a.x); r[1] = (short)f2b(a.y);
    r[2] = (short)f2b(a.z); r[3] = (short)f2b(a.w);
    r[4] = (short)f2b(b.x); r[5] = (short)f2b(b.y);
    r[6] = (short)f2b(b.z); r[7] = (short)f2b(b.w);
    return r;
}

// True iff the buffer is fp32 (some 16-bit half decodes to bf16 exp >= 150,
// i.e. |v| >= 2^23 — impossible for real N(0,1)-scale bf16 token data).
__device__ __forceinline__ bool buf_is_f32(const uint32_t* t) {
    int cnt = 0;
    #pragma unroll 8
    for (int i = 0; i < 64; ++i) {
        const uint32_t w = t[i];
        cnt += (((w >> 7) & 0xFFu) >= 150u);
        cnt += (((w >> 23) & 0xFFu) >= 150u);
    }
    return cnt != 0;
}

template<bool F32>
__global__ __launch_bounds__(256, 2)
void cmaa_fused(const void* __restrict__ tokv,
                const void* __restrict__ Wqv,
                const void* __restrict__ Wkv,
                const void* __restrict__ Wvv,
                const void* __restrict__ Wrv,
                const void* __restrict__ Wov,
                const void* __restrict__ lngv,
                const void* __restrict__ lnbv,
                void* __restrict__ outv)
{
    if (buf_is_f32((const uint32_t*)tokv) != F32) return;  // uniform: no barrier yet

    __shared__ __align__(16) uint16_t sX [RT * SX_LD];
    __shared__ __align__(16) uint16_t sQK[RT * SQK_LD];   // reused as fp32 sY
    __shared__ __align__(16) uint16_t sAO[RT * SAO_LD];

    const int tid  = threadIdx.x;
    const int wv   = tid >> 6;
    const int lane = tid & 63;
    const int l15  = lane & 15;
    const int quad = lane >> 4;
    const int R0   = blockIdx.x * RT;

    const float*    tokF = (const float*)tokv;
    const uint16_t* tokB = (const uint16_t*)tokv;

    // ---------------- stage 0: X tile -> LDS (bf16) ----------------
    if constexpr (F32) {
        const float* g = tokF + (size_t)R0 * D_DIM;
        for (int t = tid; t < RT * (D_DIM / 8); t += 256) {
            const int row = t >> 5, c = t & 31;
            *(bf16x8*)&sX[row * SX_LD + c * 8] = cvt8(&g[row * D_DIM + c * 8]);
        }
    } else {
        const uint4* g = (const uint4*)(tokB + (size_t)R0 * D_DIM);
        for (int t = tid; t < RT * (D_DIM / 8); t += 256) {
            const int row = t >> 5, c = t & 31;
            *(uint4*)&sX[row * SX_LD + c * 8] = g[t];
        }
    }
    __syncthreads();

    const void* Wsel = (wv == 0) ? Wqv : (wv == 1) ? Wkv : (wv == 2) ? Wvv : Wrv;
    const float*    WsF = (const float*)Wsel;
    const uint16_t* WsB = (const uint16_t*)Wsel;

    for (int p = 0; p < 2; ++p) {
        // ---------- QKVR GEMM: this phase's 128 cols of each matrix ----------
        f32x4 acc[2][8];
        #pragma unroll
        for (int mt = 0; mt < 2; ++mt)
            #pragma unroll
            for (int nt = 0; nt < 8; ++nt)
                acc[mt][nt] = (f32x4){0.f, 0.f, 0.f, 0.f};

        #pragma unroll
        for (int kk = 0; kk < 8; ++kk) {
            const int k0 = kk * 32;
            const bf16x8 a0 = *(const bf16x8*)&sX[ l15       * SX_LD + k0 + quad * 8];
            const bf16x8 a1 = *(const bf16x8*)&sX[(16 + l15) * SX_LD + k0 + quad * 8];
            #pragma unroll
            for (int nt = 0; nt < 8; ++nt) {
                const int wrow = p * 128 + nt * 16 + l15;   // W row = output col
                bf16x8 bfr;
                if constexpr (F32) bfr = cvt8(&WsF[(size_t)wrow * D_DIM + k0 + quad * 8]);
                else               bfr = *(const bf16x8*)&WsB[(size_t)wrow * D_DIM + k0 + quad * 8];
                acc[0][nt] = __builtin_amdgcn_mfma_f32_16x16x32_bf16(a0, bfr, acc[0][nt], 0, 0, 0);
                acc[1][nt] = __builtin_amdgcn_mfma_f32_16x16x32_bf16(a1, bfr, acc[1][nt], 0, 0, 0);
            }
        }
        // C layout: col=lane&15, row=quad*4+reg
        #pragma unroll
        for (int mt = 0; mt < 2; ++mt)
            #pragma unroll
            for (int nt = 0; nt < 8; ++nt)
                #pragma unroll
                for (int r = 0; r < 4; ++r) {
                    const int row = mt * 16 + quad * 4 + r;
                    const int col = wv * 128 + nt * 16 + l15;
                    sQK[row * SQK_LD + col] = f2b(acc[mt][nt][r]);
                }
        __syncthreads();

        // ---------- attention, heads p*4 .. p*4+3 ----------
        if (tid < 128) {
            const int r  = tid >> 2;
            const int h4 = tid & 3;
            const int gr = R0 + r;
            const int i  = r & 3;
            const int rb = r & ~3;
            const int h  = p * 4 + h4;

            float q[DH];
            #pragma unroll
            for (int t = 0; t < 4; ++t) {
                const bf16x8 v = *(const bf16x8*)&sQK[r * SQK_LD + h4 * DH + t * 8];
                #pragma unroll
                for (int j = 0; j < 8; ++j) q[t * 8 + j] = b2f((uint16_t)v[j]);
            }
            int rn[3];
            #pragma unroll
            for (int l = 0; l < 3; ++l) { const int jj = l + (l >= i); rn[l] = rb + jj; }

            float sc[3];
            #pragma unroll
            for (int l = 0; l < 3; ++l) {
                float s = 0.f;
                #pragma unroll
                for (int t = 0; t < 4; ++t) {
                    const bf16x8 v = *(const bf16x8*)&sQK[rn[l] * SQK_LD + 128 + h4 * DH + t * 8];
                    #pragma unroll
                    for (int j = 0; j < 8; ++j) s += q[t * 8 + j] * b2f((uint16_t)v[j]);
                }
                sc[l] = s * SCALE_F;
            }
            const float mx = fmaxf(sc[0], fmaxf(sc[1], sc[2]));
            const float e0 = __expf(sc[0] - mx), e1 = __expf(sc[1] - mx), e2 = __expf(sc[2] - mx);
            const float inv = 1.f / (e0 + e1 + e2);
            const float al[3] = { e0 * inv, e1 * inv, e2 * inv };

            if constexpr (F32) {
                float* ap = (float*)outv + Y_SZ + ((size_t)gr * H_NUM + h) * 3;
                ap[0] = al[0]; ap[1] = al[1]; ap[2] = al[2];
            } else {
                uint16_t* ap = (uint16_t*)outv + Y_SZ + ((size_t)gr * H_NUM + h) * 3;
                ap[0] = f2b(al[0]); ap[1] = f2b(al[1]); ap[2] = f2b(al[2]);
            }

            #pragma unroll
            for (int t = 0; t < 4; ++t) {
                float o[8] = {0.f,0.f,0.f,0.f,0.f,0.f,0.f,0.f};
                #pragma unroll
                for (int l = 0; l < 3; ++l) {
                    const bf16x8 vv = *(const bf16x8*)&sQK[rn[l] * SQK_LD + 256 + h4 * DH + t * 8];
                    const bf16x8 rr = *(const bf16x8*)&sQK[rn[l] * SQK_LD + 384 + h4 * DH + t * 8];
                    #pragma unroll
                    for (int j = 0; j < 8; ++j) {
                        const float rvf = b2f((uint16_t)rr[j]);
                        const float sig = 1.f / (1.f + __expf(-rvf));
                        o[j] += al[l] * sig * b2f((uint16_t)vv[j]);
                    }
                }
                bf16x8 pk;
                #pragma unroll
                for (int j = 0; j < 8; ++j) pk[j] = (short)f2b(o[j]);
                *(bf16x8*)&sAO[r * SAO_LD + h * DH + t * 8] = pk;
            }
        }
        __syncthreads();
    }

    // ---------------- stage 3: AO @ Wo^T + residual -> sY(fp32) ----------------
    f32x4 acc3[2][4];
    #pragma unroll
    for (int mt = 0; mt < 2; ++mt)
        #pragma unroll
        for (int nt = 0; nt < 4; ++nt)
            acc3[mt][nt] = (f32x4){0.f, 0.f, 0.f, 0.f};

    const float*    WoF = (const float*)Wov;
    const uint16_t* WoB = (const uint16_t*)Wov;
    #pragma unroll
    for (int kk = 0; kk < 8; ++kk) {
        const int k0 = kk * 32;
        const bf16x8 a0 = *(const bf16x8*)&sAO[ l15       * SAO_LD + k0 + quad * 8];
        const bf16x8 a1 = *(const bf16x8*)&sAO[(16 + l15) * SAO_LD + k0 + quad * 8];
        #pragma unroll
        for (int nt = 0; nt < 4; ++nt) {
            const int wrow = wv * 64 + nt * 16 + l15;
            bf16x8 bfr;
            if constexpr (F32) bfr = cvt8(&WoF[(size_t)wrow * D_DIM + k0 + quad * 8]);
            else               bfr = *(const bf16x8*)&WoB[(size_t)wrow * D_DIM + k0 + quad * 8];
            acc3[0][nt] = __builtin_amdgcn_mfma_f32_16x16x32_bf16(a0, bfr, acc3[0][nt], 0, 0, 0);
            acc3[1][nt] = __builtin_amdgcn_mfma_f32_16x16x32_bf16(a1, bfr, acc3[1][nt], 0, 0, 0);
        }
    }
    float* sY = (float*)sQK;   // barrier-protected reuse
    #pragma unroll
    for (int mt = 0; mt < 2; ++mt)
        #pragma unroll
        for (int nt = 0; nt < 4; ++nt)
            #pragma unroll
            for (int r = 0; r < 4; ++r) {
                const int row = mt * 16 + quad * 4 + r;
                const int col = wv * 64 + nt * 16 + l15;
                float resid;
                if constexpr (F32) resid = tokF[(size_t)(R0 + row) * D_DIM + col];
                else               resid = b2f(sX[row * SX_LD + col]);
                sY[row * SY_LD + col] = acc3[mt][nt][r] + resid;
            }
    __syncthreads();

    // ---------------- two-pass LayerNorm + store y ----------------
    {
        const int row = tid >> 3;   // 32 rows x 8 lanes (within-wave groups)
        const int sub = tid & 7;
        float vals[32];
        float s = 0.f;
        #pragma unroll
        for (int j = 0; j < 8; ++j) {
            const float4 v = *(const float4*)&sY[row * SY_LD + j * 32 + sub * 4];
            vals[j*4+0] = v.x; vals[j*4+1] = v.y; vals[j*4+2] = v.z; vals[j*4+3] = v.w;
            s += v.x + v.y + v.z + v.w;
        }
        s += __shfl_xor(s, 1); s += __shfl_xor(s, 2); s += __shfl_xor(s, 4);
        const float mean = s * (1.f / 256.f);
        float s2 = 0.f;
        #pragma unroll
        for (int j = 0; j < 32; ++j) { const float d = vals[j] - mean; s2 += d * d; }
        s2 += __shfl_xor(s2, 1); s2 += __shfl_xor(s2, 2); s2 += __shfl_xor(s2, 4);
        const float var  = fmaxf(s2 * (1.f / 256.f), 0.f);
        const float rstd = rsqrtf(var + 1e-5f);

        #pragma unroll
        for (int j = 0; j < 8; ++j) {
            const int col = j * 32 + sub * 4;
            float g0, g1, g2, g3, b0, b1, b2, b3;
            if constexpr (F32) {
                const float4 g4 = *(const float4*)&((const float*)lngv)[col];
                const float4 b4 = *(const float4*)&((const float*)lnbv)[col];
                g0 = g4.x; g1 = g4.y; g2 = g4.z; g3 = g4.w;
                b0 = b4.x; b1 = b4.y; b2 = b4.z; b3 = b4.w;
            } else {
                const ushort4 g4 = *(const ushort4*)&((const uint16_t*)lngv)[col];
                const ushort4 b4 = *(const ushort4*)&((const uint16_t*)lnbv)[col];
                g0 = b2f(g4.x); g1 = b2f(g4.y); g2 = b2f(g4.z); g3 = b2f(g4.w);
                b0 = b2f(b4.x); b1 = b2f(b4.y); b2 = b2f(b4.z); b3 = b2f(b4.w);
            }
            const float y0 = (vals[j*4+0] - mean) * rstd * g0 + b0;
            const float y1 = (vals[j*4+1] - mean) * rstd * g1 + b1;
            const float y2 = (vals[j*4+2] - mean) * rstd * g2 + b2;
            const float y3 = (vals[j*4+3] - mean) * rstd * g3 + b3;
            if constexpr (F32) {
                float* orow = (float*)outv + (size_t)(R0 + row) * D_DIM;
                float4 o4; o4.x = y0; o4.y = y1; o4.z = y2; o4.w = y3;
                *(float4*)&orow[col] = o4;
            } else {
                uint16_t* orow = (uint16_t*)outv + (size_t)(R0 + row) * D_DIM;
                uint2 pk;
                pk.x = (uint32_t)f2b(y0) | ((uint32_t)f2b(y1) << 16);
                pk.y = (uint32_t)f2b(y2) | ((uint32_t)f2b(y3) << 16);
                *(uint2*)&orow[col] = pk;
            }
        }
    }
}

extern "C" void kernel_launch(void* const* d_in, const int* in_sizes, int n_in,
                              void* d_out, int out_size, void* d_ws, size_t ws_size,
                              hipStream_t stream) {
    (void)in_sizes; (void)n_in; (void)d_ws; (void)ws_size; (void)out_size;
    dim3 grid(ROWS_TOT / RT), block(256);
    cmaa_fused<false><<<grid, block, 0, stream>>>(
        d_in[0], d_in[1], d_in[2], d_in[3], d_in[4], d_in[5], d_in[6], d_in[7], d_out);
    cmaa_fused<true><<<grid, block, 0, stream>>>(
        d_in[0], d_in[1], d_in[2], d_in[3], d_in[4], d_in[5], d_in[6], d_in[7], d_out);
}

// Round 3
// 540.559 us; speedup vs baseline: 1.6348x; 1.6348x over previous
//
#include <hip/hip_runtime.h>
#include <stdint.h>

// CMAALayer fused kernel, MI355X gfx950. Round 3.
// Inputs/outputs confirmed fp32 (round 2). Two kernels:
//   K0: convert the 5 weight matrices fp32 -> bf16 into d_ws (once per call).
//   K1: fused layer. One 256-thread block per RT=32 rows (8 token groups):
//     stage0: tokens -> sX (bf16)
//     phase p in {0,1}: QKVR GEMM (mfma_f32_16x16x32_bf16, bf16 weights from
//       d_ws, 1 dwordx4 per fragment) -> sQK; 3-neighbor softmax attention +
//       sigmoid(R)*V for heads p*4..p*4+3 -> sAO + attn probs (fp32) out.
//     stage3: AO @ Wo^T + residual(sX) -> sY(fp32, aliases sQK) -> LN -> y.
// Fallback template path (WBF16=false) reads fp32 weights directly if ws_size
// is too small for the converted copy.

#define D_DIM   256
#define H_NUM   8
#define DH      32
#define RT      32
#define ROWS_TOT 131072
#define Y_SZ    33554432          // 131072*256
#define SCALE_F 0.17677669529663687f
#define W_ELEMS 65536             // 256*256 per matrix
#define WS_NEED (5 * W_ELEMS * 2) // bytes for bf16 weight copy

#define SX_LD   264   // shorts
#define SQK_LD  520   // shorts
#define SAO_LD  264   // shorts
#define SY_LD   260   // floats (aliases sQK storage)

typedef __attribute__((ext_vector_type(8))) short bf16x8;
typedef __attribute__((ext_vector_type(4))) float f32x4;

__device__ __forceinline__ float b2f(uint16_t s) {
    union { uint32_t u; float f; } c; c.u = ((uint32_t)s) << 16; return c.f;
}
__device__ __forceinline__ uint16_t f2b(float f) {
    union { float f; uint32_t u; } c; c.f = f;
    return (uint16_t)((c.u + 0x7fffu + ((c.u >> 16) & 1u)) >> 16);
}
__device__ __forceinline__ bf16x8 cvt8(const float* p) {
    const float4 a = *(const float4*)p;
    const float4 b = *(const float4*)(p + 4);
    bf16x8 r;
    r[0] = (short)f2b(a.x); r[1] = (short)f2b(a.y);
    r[2] = (short)f2b(a.z); r[3] = (short)f2b(a.w);
    r[4] = (short)f2b(b.x); r[5] = (short)f2b(b.y);
    r[6] = (short)f2b(b.z); r[7] = (short)f2b(b.w);
    return r;
}

// ---------------- K0: weight fp32 -> bf16 conversion ----------------
// grid 320 blocks x 256 thr; 64 blocks per matrix (uniform matrix per block).
__global__ __launch_bounds__(256)
void conv_weights(const float* __restrict__ Wq, const float* __restrict__ Wk,
                  const float* __restrict__ Wv, const float* __restrict__ Wr,
                  const float* __restrict__ Wo, uint16_t* __restrict__ dst)
{
    const int m = blockIdx.x >> 6;                 // matrix id 0..4
    const float* src = (m == 0) ? Wq : (m == 1) ? Wk : (m == 2) ? Wv
                     : (m == 3) ? Wr : Wo;
    const int base = (blockIdx.x & 63) * 1024 + threadIdx.x * 4;  // elem idx in matrix
    const float4 v = *(const float4*)&src[base];
    uint2 pk;
    pk.x = (uint32_t)f2b(v.x) | ((uint32_t)f2b(v.y) << 16);
    pk.y = (uint32_t)f2b(v.z) | ((uint32_t)f2b(v.w) << 16);
    *(uint2*)&dst[(size_t)m * W_ELEMS + base] = pk;
}

// ---------------- K1: fused layer ----------------
template<bool WBF16>
__global__ __launch_bounds__(256, 2)
void cmaa_fused(const float* __restrict__ tok,
                const float* __restrict__ Wq, const float* __restrict__ Wk,
                const float* __restrict__ Wv, const float* __restrict__ Wr,
                const float* __restrict__ Wo,
                const uint16_t* __restrict__ wbf,   // d_ws bf16 weights (WBF16)
                const float* __restrict__ lng, const float* __restrict__ lnb,
                float* __restrict__ outp)
{
    __shared__ __align__(16) uint16_t sX [RT * SX_LD];
    __shared__ __align__(16) uint16_t sQK[RT * SQK_LD];   // reused as fp32 sY
    __shared__ __align__(16) uint16_t sAO[RT * SAO_LD];

    const int tid  = threadIdx.x;
    const int wv   = tid >> 6;
    const int lane = tid & 63;
    const int l15  = lane & 15;
    const int quad = lane >> 4;
    const int R0   = blockIdx.x * RT;

    // ---------------- stage 0: X tile -> LDS (bf16) ----------------
    {
        const float* g = tok + (size_t)R0 * D_DIM;
        for (int t = tid; t < RT * (D_DIM / 8); t += 256) {
            const int row = t >> 5, c = t & 31;
            *(bf16x8*)&sX[row * SX_LD + c * 8] = cvt8(&g[row * D_DIM + c * 8]);
        }
    }
    __syncthreads();

    // wave w owns one projection matrix (cols [w*128, w*128+128) of sQK)
    const float*    WselF = (wv == 0) ? Wq : (wv == 1) ? Wk : (wv == 2) ? Wv : Wr;
    const uint16_t* WselB = wbf + (size_t)wv * W_ELEMS;

    for (int p = 0; p < 2; ++p) {
        // ---------- QKVR GEMM: this phase's 128 cols per matrix ----------
        f32x4 acc[2][8];
        #pragma unroll
        for (int mt = 0; mt < 2; ++mt)
            #pragma unroll
            for (int nt = 0; nt < 8; ++nt)
                acc[mt][nt] = (f32x4){0.f, 0.f, 0.f, 0.f};

        #pragma unroll
        for (int kk = 0; kk < 8; ++kk) {
            const int k0 = kk * 32;
            const bf16x8 a0 = *(const bf16x8*)&sX[ l15       * SX_LD + k0 + quad * 8];
            const bf16x8 a1 = *(const bf16x8*)&sX[(16 + l15) * SX_LD + k0 + quad * 8];
            bf16x8 bw[8];
            #pragma unroll
            for (int nt = 0; nt < 8; ++nt) {
                const int wrow = p * 128 + nt * 16 + l15;   // W row = output col
                if constexpr (WBF16)
                    bw[nt] = *(const bf16x8*)&WselB[(size_t)wrow * D_DIM + k0 + quad * 8];
                else
                    bw[nt] = cvt8(&WselF[(size_t)wrow * D_DIM + k0 + quad * 8]);
            }
            #pragma unroll
            for (int nt = 0; nt < 8; ++nt) {
                acc[0][nt] = __builtin_amdgcn_mfma_f32_16x16x32_bf16(a0, bw[nt], acc[0][nt], 0, 0, 0);
                acc[1][nt] = __builtin_amdgcn_mfma_f32_16x16x32_bf16(a1, bw[nt], acc[1][nt], 0, 0, 0);
            }
        }
        // C layout: col=lane&15, row=quad*4+reg
        #pragma unroll
        for (int mt = 0; mt < 2; ++mt)
            #pragma unroll
            for (int nt = 0; nt < 8; ++nt)
                #pragma unroll
                for (int r = 0; r < 4; ++r) {
                    const int row = mt * 16 + quad * 4 + r;
                    const int col = wv * 128 + nt * 16 + l15;
                    sQK[row * SQK_LD + col] = f2b(acc[mt][nt][r]);
                }
        __syncthreads();

        // ---------- attention, heads p*4 .. p*4+3 ----------
        if (tid < 128) {
            const int r  = tid >> 2;
            const int h4 = tid & 3;
            const int gr = R0 + r;
            const int i  = r & 3;
            const int rb = r & ~3;
            const int h  = p * 4 + h4;

            float q[DH];
            #pragma unroll
            for (int t = 0; t < 4; ++t) {
                const bf16x8 v = *(const bf16x8*)&sQK[r * SQK_LD + h4 * DH + t * 8];
                #pragma unroll
                for (int j = 0; j < 8; ++j) q[t * 8 + j] = b2f((uint16_t)v[j]);
            }
            int rn[3];
            #pragma unroll
            for (int l = 0; l < 3; ++l) { const int jj = l + (l >= i); rn[l] = rb + jj; }

            float sc[3];
            #pragma unroll
            for (int l = 0; l < 3; ++l) {
                float s = 0.f;
                #pragma unroll
                for (int t = 0; t < 4; ++t) {
                    const bf16x8 v = *(const bf16x8*)&sQK[rn[l] * SQK_LD + 128 + h4 * DH + t * 8];
                    #pragma unroll
                    for (int j = 0; j < 8; ++j) s += q[t * 8 + j] * b2f((uint16_t)v[j]);
                }
                sc[l] = s * SCALE_F;
            }
            const float mx = fmaxf(sc[0], fmaxf(sc[1], sc[2]));
            const float e0 = __expf(sc[0] - mx), e1 = __expf(sc[1] - mx), e2 = __expf(sc[2] - mx);
            const float inv = 1.f / (e0 + e1 + e2);
            const float al[3] = { e0 * inv, e1 * inv, e2 * inv };

            float* ap = outp + Y_SZ + ((size_t)gr * H_NUM + h) * 3;
            ap[0] = al[0]; ap[1] = al[1]; ap[2] = al[2];

            #pragma unroll
            for (int t = 0; t < 4; ++t) {
                float o[8] = {0.f,0.f,0.f,0.f,0.f,0.f,0.f,0.f};
                #pragma unroll
                for (int l = 0; l < 3; ++l) {
                    const bf16x8 vv = *(const bf16x8*)&sQK[rn[l] * SQK_LD + 256 + h4 * DH + t * 8];
                    const bf16x8 rr = *(const bf16x8*)&sQK[rn[l] * SQK_LD + 384 + h4 * DH + t * 8];
                    #pragma unroll
                    for (int j = 0; j < 8; ++j) {
                        const float rvf = b2f((uint16_t)rr[j]);
                        const float sig = 1.f / (1.f + __expf(-rvf));
                        o[j] += al[l] * sig * b2f((uint16_t)vv[j]);
                    }
                }
                bf16x8 pk;
                #pragma unroll
                for (int j = 0; j < 8; ++j) pk[j] = (short)f2b(o[j]);
                *(bf16x8*)&sAO[r * SAO_LD + h * DH + t * 8] = pk;
            }
        }
        __syncthreads();
    }

    // ---------------- stage 3: AO @ Wo^T + residual -> sY(fp32) ----------------
    f32x4 acc3[2][4];
    #pragma unroll
    for (int mt = 0; mt < 2; ++mt)
        #pragma unroll
        for (int nt = 0; nt < 4; ++nt)
            acc3[mt][nt] = (f32x4){0.f, 0.f, 0.f, 0.f};

    const uint16_t* WoB = wbf + (size_t)4 * W_ELEMS;
    #pragma unroll
    for (int kk = 0; kk < 8; ++kk) {
        const int k0 = kk * 32;
        const bf16x8 a0 = *(const bf16x8*)&sAO[ l15       * SAO_LD + k0 + quad * 8];
        const bf16x8 a1 = *(const bf16x8*)&sAO[(16 + l15) * SAO_LD + k0 + quad * 8];
        bf16x8 bw[4];
        #pragma unroll
        for (int nt = 0; nt < 4; ++nt) {
            const int wrow = wv * 64 + nt * 16 + l15;
            if constexpr (WBF16)
                bw[nt] = *(const bf16x8*)&WoB[(size_t)wrow * D_DIM + k0 + quad * 8];
            else
                bw[nt] = cvt8(&Wo[(size_t)wrow * D_DIM + k0 + quad * 8]);
        }
        #pragma unroll
        for (int nt = 0; nt < 4; ++nt) {
            acc3[0][nt] = __builtin_amdgcn_mfma_f32_16x16x32_bf16(a0, bw[nt], acc3[0][nt], 0, 0, 0);
            acc3[1][nt] = __builtin_amdgcn_mfma_f32_16x16x32_bf16(a1, bw[nt], acc3[1][nt], 0, 0, 0);
        }
    }
    float* sY = (float*)sQK;   // barrier-protected reuse
    #pragma unroll
    for (int mt = 0; mt < 2; ++mt)
        #pragma unroll
        for (int nt = 0; nt < 4; ++nt)
            #pragma unroll
            for (int r = 0; r < 4; ++r) {
                const int row = mt * 16 + quad * 4 + r;
                const int col = wv * 64 + nt * 16 + l15;
                sY[row * SY_LD + col] = acc3[mt][nt][r] + b2f(sX[row * SX_LD + col]);
            }
    __syncthreads();

    // ---------------- two-pass LayerNorm + store y ----------------
    {
        const int row = tid >> 3;   // 32 rows x 8 lanes (within-wave groups)
        const int sub = tid & 7;
        float vals[32];
        float s = 0.f;
        #pragma unroll
        for (int j = 0; j < 8; ++j) {
            const float4 v = *(const float4*)&sY[row * SY_LD + j * 32 + sub * 4];
            vals[j*4+0] = v.x; vals[j*4+1] = v.y; vals[j*4+2] = v.z; vals[j*4+3] = v.w;
            s += v.x + v.y + v.z + v.w;
        }
        s += __shfl_xor(s, 1); s += __shfl_xor(s, 2); s += __shfl_xor(s, 4);
        const float mean = s * (1.f / 256.f);
        float s2 = 0.f;
        #pragma unroll
        for (int j = 0; j < 32; ++j) { const float d = vals[j] - mean; s2 += d * d; }
        s2 += __shfl_xor(s2, 1); s2 += __shfl_xor(s2, 2); s2 += __shfl_xor(s2, 4);
        const float var  = fmaxf(s2 * (1.f / 256.f), 0.f);
        const float rstd = rsqrtf(var + 1e-5f);

        float* orow = outp + (size_t)(R0 + row) * D_DIM;
        #pragma unroll
        for (int j = 0; j < 8; ++j) {
            const int col = j * 32 + sub * 4;
            const float4 g4 = *(const float4*)&lng[col];
            const float4 b4 = *(const float4*)&lnb[col];
            float4 o4;
            o4.x = (vals[j*4+0] - mean) * rstd * g4.x + b4.x;
            o4.y = (vals[j*4+1] - mean) * rstd * g4.y + b4.y;
            o4.z = (vals[j*4+2] - mean) * rstd * g4.z + b4.z;
            o4.w = (vals[j*4+3] - mean) * rstd * g4.w + b4.w;
            *(float4*)&orow[col] = o4;
        }
    }
}

extern "C" void kernel_launch(void* const* d_in, const int* in_sizes, int n_in,
                              void* d_out, int out_size, void* d_ws, size_t ws_size,
                              hipStream_t stream) {
    (void)in_sizes; (void)n_in; (void)out_size;
    const float* tok = (const float*)d_in[0];
    const float* Wq  = (const float*)d_in[1];
    const float* Wk  = (const float*)d_in[2];
    const float* Wv  = (const float*)d_in[3];
    const float* Wr  = (const float*)d_in[4];
    const float* Wo  = (const float*)d_in[5];
    const float* lng = (const float*)d_in[6];
    const float* lnb = (const float*)d_in[7];
    float* outp = (float*)d_out;
    uint16_t* wbf = (uint16_t*)d_ws;

    dim3 grid(ROWS_TOT / RT), block(256);
    if (ws_size >= (size_t)WS_NEED) {
        conv_weights<<<dim3(320), dim3(256), 0, stream>>>(Wq, Wk, Wv, Wr, Wo, wbf);
        cmaa_fused<true><<<grid, block, 0, stream>>>(
            tok, Wq, Wk, Wv, Wr, Wo, wbf, lng, lnb, outp);
    } else {
        cmaa_fused<false><<<grid, block, 0, stream>>>(
            tok, Wq, Wk, Wv, Wr, Wo, wbf, lng, lnb, outp);
    }
}